// Round 3
// baseline (2300.975 us; speedup 1.0000x reference)
//
#include <hip/hip_runtime.h>
#include <hip/hip_bf16.h>
#include <cfloat>
#include <climits>

typedef short  short8v __attribute__((ext_vector_type(8)));
typedef float  f32x4   __attribute__((ext_vector_type(4)));

#define NQ     128  // number of queries (fixed by problem)
#define RPW    256  // pool rows per wave (16 iterations x 16 rows)
#define ITERS  16
#define K1     4    // per-(lane,tile) and per-wave top-k in phase 1
#define K2     6    // per-thread top-k in phase 2 stream scan
#define KSEL   24   // approx top-K kept for exact rescore (margin over 10)
#define KK     10   // final k

__device__ __forceinline__ bool pair_less(float d1, int i1, float d2, int i2) {
    return (d1 < d2) || (d1 == d2 && i1 < i2);
}

// packed fp32x2 -> bf16x2 (RNE); lowers to v_cvt_pk_bf16_f32 on gfx950
__device__ __forceinline__ unsigned pk2(float a, float b) {
    union { __hip_bfloat162 h; unsigned u; } cv;
    cv.h = __float22bfloat162_rn(make_float2(a, b));
    return cv.u;
}
__device__ __forceinline__ short8v pack8(float4 a, float4 b) {
    union { unsigned u[4]; short8v s; } cv;
    cv.u[0] = pk2(a.x, a.y); cv.u[1] = pk2(a.z, a.w);
    cv.u[2] = pk2(b.x, b.y); cv.u[3] = pk2(b.z, b.w);
    return cv.s;
}

// Sorted-ascending top-4 insert, key-only compare. Caller feeds keys in
// ascending-index order, so strict < keeps earliest-index-wins on ties.
__device__ __forceinline__ void ins4(float (&d)[K1], int (&ix)[K1], float key, int idx) {
    if (!(key < d[K1 - 1])) return;
    d[K1 - 1] = key; ix[K1 - 1] = idx;
#pragma unroll
    for (int j = K1 - 1; j > 0; --j) {
        float a = d[j - 1], b = d[j]; int ai = ix[j - 1], bi = ix[j];
        bool sw = b < a;
        d[j - 1] = sw ? b : a; ix[j - 1] = sw ? bi : ai;
        d[j]     = sw ? a : b; ix[j]     = sw ? ai : bi;
    }
}

// (key,idx)-ordered top-4 insert, used in the cross-lane end merge.
__device__ __forceinline__ void ins4p(float (&d)[K1], int (&ix)[K1], float key, int idx) {
    if (!pair_less(key, idx, d[K1 - 1], ix[K1 - 1])) return;
    d[K1 - 1] = key; ix[K1 - 1] = idx;
#pragma unroll
    for (int j = K1 - 1; j > 0; --j) {
        float a = d[j - 1], b = d[j]; int ai = ix[j - 1], bi = ix[j];
        bool sw = pair_less(b, bi, a, ai);
        d[j - 1] = sw ? b : a; ix[j - 1] = sw ? bi : ai;
        d[j]     = sw ? a : b; ix[j]     = sw ? ai : bi;
    }
}

__device__ __forceinline__ void ins6(float (&d)[K2], int (&ix)[K2], float key, int idx) {
    if (!pair_less(key, idx, d[K2 - 1], ix[K2 - 1])) return;
    d[K2 - 1] = key; ix[K2 - 1] = idx;
#pragma unroll
    for (int j = K2 - 1; j > 0; --j) {
        float a = d[j - 1], b = d[j]; int ai = ix[j - 1], bi = ix[j];
        bool sw = pair_less(b, bi, a, ai);
        d[j - 1] = sw ? b : a; ix[j - 1] = sw ? bi : ai;
        d[j]     = sw ? a : b; ix[j]     = sw ? ai : bi;
    }
}

__device__ __forceinline__ void argmin64(float& k, int& i, int& l) {
#pragma unroll
    for (int off = 32; off; off >>= 1) {
        float ok = __shfl_xor(k, off);
        int   oi = __shfl_xor(i, off);
        int   ol = __shfl_xor(l, off);
        bool take = pair_less(ok, oi, k, i) || (ok == k && oi == i && ol < l);
        k = take ? ok : k; i = take ? oi : i; l = take ? ol : l;
    }
}

// ---------------- Phase 1: LDS-free, barrier-free MFMA scoring --------------
// One wave owns a contiguous 256-row pool strip and scores it against all 128
// queries. B-fragments (queries, pre-scaled by -2, bf16) live in VGPRs; pool
// rows are loaded straight into A-fragment lane layout (m=lane&15,
// k=(lane>>4)*8+j), converted in-register; psq enters via the MFMA C operand.
__global__ __launch_bounds__(256, 2) void phase1(
        const float* __restrict__ x, const float* __restrict__ pool_x,
        float2* __restrict__ cand, int N, int Wtot) {
    const int t = threadIdx.x, wv = t >> 6, lane = t & 63;
    const int c = lane & 15, g = lane >> 4;
    const int w = blockIdx.x * 4 + wv;            // global wave id
    const long base_row = (long)w * RPW;

    // ---- B fragments: B'[k][q] = bf16(-2 * x[q][k]); n=lane&15, k=g*8+j.
    short8v bfrag[8][2];
#pragma unroll
    for (int tt = 0; tt < 8; ++tt)
#pragma unroll
        for (int ks = 0; ks < 2; ++ks) {
            const float* xp = x + (tt * 16 + c) * 64 + ks * 32 + g * 8;
            float4 u0 = *(const float4*)xp;
            float4 u1 = *(const float4*)(xp + 4);
            u0.x *= -2.f; u0.y *= -2.f; u0.z *= -2.f; u0.w *= -2.f;
            u1.x *= -2.f; u1.y *= -2.f; u1.z *= -2.f; u1.w *= -2.f;
            bfrag[tt][ks] = pack8(u0, u1);
        }

    float bd[8][K1]; int bi[8][K1];
#pragma unroll
    for (int tt = 0; tt < 8; ++tt)
#pragma unroll
        for (int j = 0; j < K1; ++j) { bd[tt][j] = FLT_MAX; bi[tt][j] = INT_MAX; }

    // ---- main loop: distance-2 register prefetch, 3 rotating buffers.
    float4 fb[3][4];
    const long nclamp = (long)N - 1;
    auto LOAD = [&](int it, int b) {
        long row = base_row + it * 16 + c;
        long rowc = row < nclamp ? row : nclamp;
        const float4* pr = (const float4*)pool_x + rowc * 16;
        fb[b][0] = pr[2 * g];     fb[b][1] = pr[2 * g + 1];
        fb[b][2] = pr[8 + 2 * g]; fb[b][3] = pr[8 + 2 * g + 1];
    };
    LOAD(0, 0); LOAD(1, 1);

#pragma unroll
    for (int it = 0; it < ITERS; ++it) {
        const int b = it % 3;
        if (it + 2 < ITERS) LOAD(it + 2, (it + 2) % 3);

        // psq of this lane's row (m = c): partial over its 16 dims, then
        // reduce across the 4 k-strip lanes.
        float4 q0 = fb[b][0], q1 = fb[b][1], q2 = fb[b][2], q3 = fb[b][3];
        float ps = q0.x * q0.x + q0.y * q0.y + q0.z * q0.z + q0.w * q0.w
                 + q1.x * q1.x + q1.y * q1.y + q1.z * q1.z + q1.w * q1.w
                 + q2.x * q2.x + q2.y * q2.y + q2.z * q2.z + q2.w * q2.w
                 + q3.x * q3.x + q3.y * q3.y + q3.z * q3.z + q3.w * q3.w;
        ps += __shfl_xor(ps, 16);
        ps += __shfl_xor(ps, 32);
        if (base_row + it * 16 + c >= N) ps = __builtin_inff();  // OOB -> never wins

        // redistribute psq to D layout: lane needs rows g*4+r.
        f32x4 psqv;
#pragma unroll
        for (int r = 0; r < 4; ++r) psqv[r] = __shfl(ps, g * 4 + r);

        short8v a0 = pack8(fb[b][0], fb[b][1]);
        short8v a1 = pack8(fb[b][2], fb[b][3]);
        const int rowb = (int)base_row + it * 16 + g * 4;

#pragma unroll
        for (int tt = 0; tt < 8; ++tt) {
            f32x4 acc = __builtin_amdgcn_mfma_f32_16x16x32_bf16(a0, bfrag[tt][0], psqv, 0, 0, 0);
            acc = __builtin_amdgcn_mfma_f32_16x16x32_bf16(a1, bfrag[tt][1], acc, 0, 0, 0);
            float mn = fminf(fminf(acc[0], acc[1]), fminf(acc[2], acc[3]));
            if (mn < bd[tt][K1 - 1]) {
#pragma unroll
                for (int r = 0; r < 4; ++r) ins4(bd[tt], bi[tt], acc[r], rowb + r);
            }
        }
    }

    // ---- end merge: butterfly across the 4 g-lanes of each query column,
    // then each lane writes slot g of the wave's per-query top-4.
#pragma unroll
    for (int tt = 0; tt < 8; ++tt) {
#pragma unroll
        for (int m = 16; m <= 32; m <<= 1) {
            float od[K1]; int oi[K1];
#pragma unroll
            for (int j = 0; j < K1; ++j) { od[j] = __shfl_xor(bd[tt][j], m); oi[j] = __shfl_xor(bi[tt][j], m); }
#pragma unroll
            for (int j = 0; j < K1; ++j) ins4p(bd[tt], bi[tt], od[j], oi[j]);
        }
        int q = tt * 16 + c;
        cand[((size_t)q * Wtot + w) * K1 + g] =
            make_float2(bd[tt][g], __int_as_float(bi[tt][g]));
    }
}

// ---------------- Phase 2: merge -> approx top-24 -> exact rescore -> top-10
__global__ __launch_bounds__(256) void phase2(
        const float2* __restrict__ cand, const float* __restrict__ x,
        const float* __restrict__ pool_x, const float* __restrict__ pool_y,
        float* __restrict__ out, int Wtot, int N) {
    __shared__ float xs[64];
    __shared__ float wd[4 * KSEL]; __shared__ int wi[4 * KSEL];
    __shared__ float sd[KSEL];     __shared__ int si[KSEL];
    __shared__ float rk[64];
    __shared__ int   fi[KK];

    const int t = threadIdx.x, wave = t >> 6, lane = t & 63;
    const int q = blockIdx.x;
    if (t < 64) xs[t] = x[q * 64 + t];

    const int M = Wtot * K1;
    float d[K2]; int ix[K2];
#pragma unroll
    for (int j = 0; j < K2; ++j) { d[j] = FLT_MAX; ix[j] = INT_MAX; }

    const float2* cq = cand + (size_t)q * M;
    for (int m = t; m < M; m += 256) {
        float2 e = cq[m];
        ins6(d, ix, e.x, __float_as_int(e.y));
    }

    // per-wave extraction of its top-KSEL (sorted lists -> iterative argmin+pop)
    for (int r = 0; r < KSEL; ++r) {
        float mk = d[0]; int mi = ix[0]; int ml = lane;
        argmin64(mk, mi, ml);
        if (lane == ml) {
#pragma unroll
            for (int j = 0; j < K2 - 1; ++j) { d[j] = d[j + 1]; ix[j] = ix[j + 1]; }
            d[K2 - 1] = FLT_MAX; ix[K2 - 1] = INT_MAX;
        }
        if (lane == 0) { wd[wave * KSEL + r] = mk; wi[wave * KSEL + r] = mi; }
    }
    __syncthreads();

    // wave 0 merges 4xKSEL=96 -> global approx top-KSEL
    if (wave == 0) {
        float e0 = wd[lane]; int e0i = wi[lane];
        float e1 = (lane + 64 < 4 * KSEL) ? wd[lane + 64] : FLT_MAX;
        int  e1i = (lane + 64 < 4 * KSEL) ? wi[lane + 64] : INT_MAX;
        if (pair_less(e1, e1i, e0, e0i)) {
            float tf = e0; e0 = e1; e1 = tf;
            int   ti = e0i; e0i = e1i; e1i = ti;
        }
        for (int r = 0; r < KSEL; ++r) {
            float mk = e0; int mi = e0i; int ml = lane;
            argmin64(mk, mi, ml);
            if (lane == ml) { e0 = e1; e0i = e1i; e1 = FLT_MAX; e1i = INT_MAX; }
            if (lane == 0) { sd[r] = mk; si[r] = mi; }
        }
    }
    __syncthreads();

    // exact fp32 rescore of the KSEL survivors
    if (t < 64) {
        float key = FLT_MAX;
        if (t < KSEL) {
            int idx = si[t];
            if (idx >= 0 && idx < N) {
                const float4* pr = (const float4*)(pool_x + (size_t)idx * 64);
                const float4* xv = (const float4*)xs;
                float psq = 0.f, dot = 0.f;
#pragma unroll
                for (int k4 = 0; k4 < 16; ++k4) {
                    float4 p = pr[k4]; float4 xw = xv[k4];
                    psq += p.x * p.x + p.y * p.y + p.z * p.z + p.w * p.w;
                    dot += p.x * xw.x + p.y * xw.y + p.z * xw.z + p.w * xw.w;
                }
                key = psq - 2.0f * dot;
            }
        }
        rk[t] = key;
    }
    __syncthreads();

    // exact top-10 by (key, idx) — matches reference ascending-sort semantics
    if (wave == 0) {
        float mykey = rk[lane];
        int myidx = (lane < KSEL) ? si[lane] : INT_MAX;
        for (int r = 0; r < KK; ++r) {
            float mk = mykey; int mi = myidx; int ml = lane;
            argmin64(mk, mi, ml);
            if (lane == ml) { mykey = FLT_MAX; myidx = INT_MAX; }
            if (lane == 0) fi[r] = mi;
        }
    }
    __syncthreads();

    // gather output rows: [q][j][0:64]=pool_x[idx], [q][j][64]=pool_y[idx]
    for (int e = t; e < KK * 65; e += 256) {
        int j = e / 65, cdim = e - j * 65;
        int idx = fi[j];
        out[(size_t)q * (KK * 65) + e] = (cdim < 64) ? pool_x[(size_t)idx * 64 + cdim]
                                                     : pool_y[idx];
    }
}

extern "C" void kernel_launch(void* const* d_in, const int* in_sizes, int n_in,
                              void* d_out, int out_size, void* d_ws, size_t ws_size,
                              hipStream_t stream) {
    const float* x      = (const float*)d_in[0];
    const float* pool_x = (const float*)d_in[1];
    const float* pool_y = (const float*)d_in[2];
    const int N = in_sizes[1] / 64;

    const int W       = (N + RPW - 1) / RPW;   // waves needed
    const int nblocks = (W + 3) / 4;           // 256-thread blocks
    const int Wtot    = nblocks * 4;           // padded wave count (layout)

    float2* cand = (float2*)d_ws;              // [NQ][Wtot*4] {key, idx-bits}

    hipLaunchKernelGGL(phase1, dim3(nblocks), dim3(256), 0, stream,
                       x, pool_x, cand, N, Wtot);
    hipLaunchKernelGGL(phase2, dim3(NQ), dim3(256), 0, stream,
                       cand, x, pool_x, pool_y, (float*)d_out, Wtot, N);
}

// Round 4
// 262.078 us; speedup vs baseline: 8.7797x; 8.7797x over previous
//
#include <hip/hip_runtime.h>
#include <hip/hip_bf16.h>
#include <cfloat>
#include <climits>

typedef short  short8v __attribute__((ext_vector_type(8)));
typedef float  f32x4   __attribute__((ext_vector_type(4)));

#define NQ    128   // queries (fixed by problem)
#define TILE  64    // pool rows per LDS tile
#define TPB   8     // tiles per block
#define RPB   (TILE * TPB)   // 512 rows per block
#define K1    4     // per-wave top-k in phase 1
#define K2    6     // per-thread top-k in phase 2 stream scan
#define KSEL  24    // approx top-K kept for exact rescore
#define KK    10    // final k

__device__ __forceinline__ bool pair_less(float d1, int i1, float d2, int i2) {
    return (d1 < d2) || (d1 == d2 && i1 < i2);
}

// packed fp32x2 -> bf16x2 (RNE)
__device__ __forceinline__ unsigned pk2(float a, float b) {
    union { __hip_bfloat162 h; unsigned u; } cv;
    cv.h = __float22bfloat162_rn(make_float2(a, b));
    return cv.u;
}
__device__ __forceinline__ short8v pack8(float4 a, float4 b) {
    union { unsigned u[4]; short8v s; } cv;
    cv.u[0] = pk2(a.x, a.y); cv.u[1] = pk2(a.z, a.w);
    cv.u[2] = pk2(b.x, b.y); cv.u[3] = pk2(b.z, b.w);
    return cv.s;
}

// async 16B global->LDS; dst is the WAVE-UNIFORM base (HW adds lane*16)
__device__ __forceinline__ void gl2lds16(const float* src, float* dst) {
    __builtin_amdgcn_global_load_lds(
        (const __attribute__((address_space(1))) void*)src,
        (__attribute__((address_space(3))) void*)dst, 16, 0, 0);
}

// Sorted-ascending top-4 insert, key-only compare (callers feed ascending idx).
__device__ __forceinline__ void ins4(float (&d)[K1], int (&ix)[K1], float key, int idx) {
    if (!(key < d[K1 - 1])) return;
    d[K1 - 1] = key; ix[K1 - 1] = idx;
#pragma unroll
    for (int j = K1 - 1; j > 0; --j) {
        float a = d[j - 1], b = d[j]; int ai = ix[j - 1], bi = ix[j];
        bool sw = b < a;
        d[j - 1] = sw ? b : a; ix[j - 1] = sw ? bi : ai;
        d[j]     = sw ? a : b; ix[j]     = sw ? ai : bi;
    }
}

// (key,idx)-ordered top-4 insert for the cross-lane end merge.
__device__ __forceinline__ void ins4p(float (&d)[K1], int (&ix)[K1], float key, int idx) {
    if (!pair_less(key, idx, d[K1 - 1], ix[K1 - 1])) return;
    d[K1 - 1] = key; ix[K1 - 1] = idx;
#pragma unroll
    for (int j = K1 - 1; j > 0; --j) {
        float a = d[j - 1], b = d[j]; int ai = ix[j - 1], bi = ix[j];
        bool sw = pair_less(b, bi, a, ai);
        d[j - 1] = sw ? b : a; ix[j - 1] = sw ? bi : ai;
        d[j]     = sw ? a : b; ix[j]     = sw ? ai : bi;
    }
}

__device__ __forceinline__ void ins6(float (&d)[K2], int (&ix)[K2], float key, int idx) {
    if (!pair_less(key, idx, d[K2 - 1], ix[K2 - 1])) return;
    d[K2 - 1] = key; ix[K2 - 1] = idx;
#pragma unroll
    for (int j = K2 - 1; j > 0; --j) {
        float a = d[j - 1], b = d[j]; int ai = ix[j - 1], bi = ix[j];
        bool sw = pair_less(b, bi, a, ai);
        d[j - 1] = sw ? b : a; ix[j - 1] = sw ? bi : ai;
        d[j]     = sw ? a : b; ix[j]     = sw ? ai : bi;
    }
}

__device__ __forceinline__ void argmin64(float& k, int& i, int& l) {
#pragma unroll
    for (int off = 32; off; off >>= 1) {
        float ok = __shfl_xor(k, off);
        int   oi = __shfl_xor(i, off);
        int   ol = __shfl_xor(l, off);
        bool take = pair_less(ok, oi, k, i) || (ok == k && oi == i && ol < l);
        k = take ? ok : k; i = take ? oi : i; l = take ? ol : l;
    }
}

// ---------------- Phase 1 -----------------------------------------------
// Block = 256 threads (4 waves). Block owns 512 pool rows; wave wv scores all
// of them against queries [32wv, 32wv+32). fp32 tiles DMA'd to LDS
// (double-buffered, rotated layout: pool chunk (r,kc) at slot (kc+r)&15 so
// ds_read_b128 fragment reads are bank-uniform while staging stays 1KB-coalesced).
__global__ __launch_bounds__(256) void phase1(
        const float* __restrict__ x, const float* __restrict__ pool_x,
        float2* __restrict__ cand, int N, int nblocks) {
    __shared__ float lds[2][TILE * 64];   // 2 x 16 KB
    const int t = threadIdx.x, wv = t >> 6, lane = t & 63;
    const int c = lane & 15, g = lane >> 4;
    const int blk = blockIdx.x;
    const long brow = (long)blk * RPB;

    // B fragments: B'[k][q] = bf16(-2 x[q][k]); n=lane&15, k=g*8+j. 16 VGPRs.
    short8v bfrag[2][2];
#pragma unroll
    for (int tt = 0; tt < 2; ++tt)
#pragma unroll
        for (int ks = 0; ks < 2; ++ks) {
            const float* xp = x + (wv * 32 + tt * 16 + c) * 64 + ks * 32 + g * 8;
            float4 u0 = *(const float4*)xp;
            float4 u1 = *(const float4*)(xp + 4);
            u0.x *= -2.f; u0.y *= -2.f; u0.z *= -2.f; u0.w *= -2.f;
            u1.x *= -2.f; u1.y *= -2.f; u1.z *= -2.f; u1.w *= -2.f;
            bfrag[tt][ks] = pack8(u0, u1);
        }

    float bd[2][K1]; int bi[2][K1];
#pragma unroll
    for (int tt = 0; tt < 2; ++tt)
#pragma unroll
        for (int j = 0; j < K1; ++j) { bd[tt][j] = FLT_MAX; bi[tt][j] = INT_MAX; }

    // Staging: 16 instrs/tile, wave wv issues k = wv*4..wv*4+3. Instruction k
    // fills rows k*4..k*4+3 (1 KB contiguous); lane -> (row k*4+(lane>>4),
    // chunk kc=((lane&15)-row)&15), i.e. rotated within each 256B row.
    auto stage = [&](int it, int buf) {
#pragma unroll
        for (int j = 0; j < 4; ++j) {
            const int k = wv * 4 + j;
            const int rl = k * 4 + g;
            long r = brow + (long)it * TILE + rl;
            if (r > N - 1) r = N - 1;
            const int kc = (c - rl) & 15;
            gl2lds16(pool_x + r * 64 + kc * 4, &lds[buf][k * 256]);
        }
    };

    stage(0, 0);
    __syncthreads();

#pragma unroll 1
    for (int it = 0; it < TPB; ++it) {
        const int buf = it & 1;
        if (it + 1 < TPB) stage(it + 1, buf ^ 1);
        const long tbase = brow + (long)it * TILE;

#pragma unroll
        for (int sr = 0; sr < 4; ++sr) {
            const int rl = sr * 16 + c;               // this lane's A-row
            const float* Lb = &lds[buf][rl * 64];
            float4 f0 = *(const float4*)(Lb + (((2 * g)     + rl & 15)) * 4);
            float4 f1 = *(const float4*)(Lb + (((2 * g + 1) + rl & 15)) * 4);
            float4 f2 = *(const float4*)(Lb + (((2 * g + 8) + rl & 15)) * 4);
            float4 f3 = *(const float4*)(Lb + (((2 * g + 9) + rl & 15)) * 4);

            // psq of row rl: partial over this lane's 16 dims, reduce over g.
            float ps = f0.x * f0.x + f0.y * f0.y + f0.z * f0.z + f0.w * f0.w
                     + f1.x * f1.x + f1.y * f1.y + f1.z * f1.z + f1.w * f1.w
                     + f2.x * f2.x + f2.y * f2.y + f2.z * f2.z + f2.w * f2.w
                     + f3.x * f3.x + f3.y * f3.y + f3.z * f3.z + f3.w * f3.w;
            ps += __shfl_xor(ps, 16);
            ps += __shfl_xor(ps, 32);
            if (tbase + rl >= N) ps = __builtin_inff();   // OOB row never wins

            f32x4 psqv;                                   // D-layout rows g*4+r
#pragma unroll
            for (int r = 0; r < 4; ++r) psqv[r] = __shfl(ps, g * 4 + r);

            short8v a0 = pack8(f0, f1);
            short8v a1 = pack8(f2, f3);
            const int rowb = (int)tbase + sr * 16 + g * 4;

#pragma unroll
            for (int tt = 0; tt < 2; ++tt) {
                f32x4 acc = __builtin_amdgcn_mfma_f32_16x16x32_bf16(a0, bfrag[tt][0], psqv, 0, 0, 0);
                acc = __builtin_amdgcn_mfma_f32_16x16x32_bf16(a1, bfrag[tt][1], acc, 0, 0, 0);
                float mn = fminf(fminf(acc[0], acc[1]), fminf(acc[2], acc[3]));
                if (mn < bd[tt][K1 - 1]) {
#pragma unroll
                    for (int r = 0; r < 4; ++r) ins4(bd[tt], bi[tt], acc[r], rowb + r);
                }
            }
        }
        __syncthreads();   // drains next-tile DMA + protects buffer reuse
    }

    // End merge: butterfly across the 4 g-lanes of each query column, then
    // lane writes slot g of the wave's per-query top-4.
#pragma unroll
    for (int tt = 0; tt < 2; ++tt) {
#pragma unroll
        for (int m = 16; m <= 32; m <<= 1) {
            float od[K1]; int oi[K1];
#pragma unroll
            for (int j = 0; j < K1; ++j) { od[j] = __shfl_xor(bd[tt][j], m); oi[j] = __shfl_xor(bi[tt][j], m); }
#pragma unroll
            for (int j = 0; j < K1; ++j) ins4p(bd[tt], bi[tt], od[j], oi[j]);
        }
        int q = wv * 32 + tt * 16 + c;
        cand[((size_t)q * nblocks + blk) * K1 + g] =
            make_float2(bd[tt][g], __int_as_float(bi[tt][g]));
    }
}

// ---------------- Phase 2: merge -> approx top-24 -> exact rescore -> top-10
__global__ __launch_bounds__(256) void phase2(
        const float2* __restrict__ cand, const float* __restrict__ x,
        const float* __restrict__ pool_x, const float* __restrict__ pool_y,
        float* __restrict__ out, int nblocks, int N) {
    __shared__ float xs[64];
    __shared__ float wd[4 * KSEL]; __shared__ int wi[4 * KSEL];
    __shared__ float sd[KSEL];     __shared__ int si[KSEL];
    __shared__ float rk[64];
    __shared__ int   fi[KK];

    const int t = threadIdx.x, wave = t >> 6, lane = t & 63;
    const int q = blockIdx.x;
    if (t < 64) xs[t] = x[q * 64 + t];

    const int M = nblocks * K1;
    float d[K2]; int ix[K2];
#pragma unroll
    for (int j = 0; j < K2; ++j) { d[j] = FLT_MAX; ix[j] = INT_MAX; }

    const float2* cq = cand + (size_t)q * M;
    for (int m = t; m < M; m += 256) {
        float2 e = cq[m];
        ins6(d, ix, e.x, __float_as_int(e.y));
    }

    // per-wave extraction of its top-KSEL
    for (int r = 0; r < KSEL; ++r) {
        float mk = d[0]; int mi = ix[0]; int ml = lane;
        argmin64(mk, mi, ml);
        if (lane == ml) {
#pragma unroll
            for (int j = 0; j < K2 - 1; ++j) { d[j] = d[j + 1]; ix[j] = ix[j + 1]; }
            d[K2 - 1] = FLT_MAX; ix[K2 - 1] = INT_MAX;
        }
        if (lane == 0) { wd[wave * KSEL + r] = mk; wi[wave * KSEL + r] = mi; }
    }
    __syncthreads();

    // wave 0 merges 4xKSEL=96 -> global approx top-KSEL
    if (wave == 0) {
        float e0 = wd[lane]; int e0i = wi[lane];
        float e1 = (lane + 64 < 4 * KSEL) ? wd[lane + 64] : FLT_MAX;
        int  e1i = (lane + 64 < 4 * KSEL) ? wi[lane + 64] : INT_MAX;
        if (pair_less(e1, e1i, e0, e0i)) {
            float tf = e0; e0 = e1; e1 = tf;
            int   ti = e0i; e0i = e1i; e1i = ti;
        }
        for (int r = 0; r < KSEL; ++r) {
            float mk = e0; int mi = e0i; int ml = lane;
            argmin64(mk, mi, ml);
            if (lane == ml) { e0 = e1; e0i = e1i; e1 = FLT_MAX; e1i = INT_MAX; }
            if (lane == 0) { sd[r] = mk; si[r] = mi; }
        }
    }
    __syncthreads();

    // exact fp32 rescore of the KSEL survivors
    if (t < 64) {
        float key = FLT_MAX;
        if (t < KSEL) {
            int idx = si[t];
            if (idx >= 0 && idx < N) {
                const float4* pr = (const float4*)(pool_x + (size_t)idx * 64);
                const float4* xv = (const float4*)xs;
                float psq = 0.f, dot = 0.f;
#pragma unroll
                for (int k4 = 0; k4 < 16; ++k4) {
                    float4 p = pr[k4]; float4 xw = xv[k4];
                    psq += p.x * p.x + p.y * p.y + p.z * p.z + p.w * p.w;
                    dot += p.x * xw.x + p.y * xw.y + p.z * xw.z + p.w * xw.w;
                }
                key = psq - 2.0f * dot;
            }
        }
        rk[t] = key;
    }
    __syncthreads();

    // exact top-10 by (key, idx)
    if (wave == 0) {
        float mykey = rk[lane];
        int myidx = (lane < KSEL) ? si[lane] : INT_MAX;
        for (int r = 0; r < KK; ++r) {
            float mk = mykey; int mi = myidx; int ml = lane;
            argmin64(mk, mi, ml);
            if (lane == ml) { mykey = FLT_MAX; myidx = INT_MAX; }
            if (lane == 0) fi[r] = mi;
        }
    }
    __syncthreads();

    // gather output rows: [q][j][0:64]=pool_x[idx], [q][j][64]=pool_y[idx]
    for (int e = t; e < KK * 65; e += 256) {
        int j = e / 65, cdim = e - j * 65;
        int idx = fi[j];
        out[(size_t)q * (KK * 65) + e] = (cdim < 64) ? pool_x[(size_t)idx * 64 + cdim]
                                                     : pool_y[idx];
    }
}

extern "C" void kernel_launch(void* const* d_in, const int* in_sizes, int n_in,
                              void* d_out, int out_size, void* d_ws, size_t ws_size,
                              hipStream_t stream) {
    const float* x      = (const float*)d_in[0];
    const float* pool_x = (const float*)d_in[1];
    const float* pool_y = (const float*)d_in[2];
    const int N = in_sizes[1] / 64;

    const int nblocks = (N + RPB - 1) / RPB;   // 977 at N=500000

    float2* cand = (float2*)d_ws;              // [NQ][nblocks*K1] {key, idx-bits}

    hipLaunchKernelGGL(phase1, dim3(nblocks), dim3(256), 0, stream,
                       x, pool_x, cand, N, nblocks);
    hipLaunchKernelGGL(phase2, dim3(NQ), dim3(256), 0, stream,
                       cand, x, pool_x, pool_y, (float*)d_out, nblocks, N);
}